// Round 3
// baseline (627.320 us; speedup 1.0000x reference)
//
#include <hip/hip_runtime.h>
#include <utility>

// Problem constants
// DIM_IN=128, DIM_OUT=128, DIM_X=256, L=256, BATCH=8192, fp32 everywhere.
#define NB 8192

// ---------- prep: cx[l] = C1[l,:]·x ; xF[k] = Fm[k,:]·x ; rLam = 1/Lam ----------
__global__ __launch_bounds__(256) void k_prep(const float* __restrict__ x,
                                              const float* __restrict__ C1,
                                              const float* __restrict__ Fm,
                                              const float* __restrict__ Lam,
                                              float* __restrict__ cx,
                                              float* __restrict__ xF,
                                              float* __restrict__ rLam) {
  const int t = threadIdx.x;  // 0..255
  float s1 = 0.f, s2 = 0.f;
  for (int i = 0; i < 256; ++i) {
    const float xi = x[i];
    s1 += C1[t * 256 + i] * xi;
    s2 += Fm[t * 256 + i] * xi;
  }
  cx[t] = s1;
  xF[t] = s2;
  rLam[t] = 1.0f / Lam[t];
}

// ---------- blocked-panel in-place Gauss-Jordan inverse of 128x128, no pivoting ----
// Input:  srcT = A^T row-major, leading dim `ld` (A[i][j] = srcT[j*ld+i])
// Output: dstT = (A^{-1})^T row-major, ld 128.
// 1024 threads: thread (r = tid&127, g = tid>>7) holds A[r][16g..16g+15] in regs.
// 8 outer steps of 16 pivots each; 3 barriers per outer step (24 total vs 128).
// Phase 1: wave 0 runs the 16 sequential pivots on the 128x16 panel slice entirely
// in registers (2 rows/lane), pivot row broadcast via __shfl — no barriers inside.
// Phase 2: rank-16 update, dense FMA, pivot-row data via broadcast float4 LDS reads.
__global__ __launch_bounds__(1024) void k_inv(const float* __restrict__ srcT, int ld,
                                              float* __restrict__ dstT) {
  __shared__ float PanelBuf[16][128];  // [j][r] panel slice (col-major)
  __shared__ float MBuf[16][128];      // [kk][r] panel transform M
  __shared__ float ArowsBuf[16][128];  // [kk][col] OLD panel-row values
  const int tid = threadIdx.x;
  const int r = tid & 127;
  const int g = tid >> 7;
  float a[16];
#pragma unroll
  for (int j = 0; j < 16; ++j) a[j] = srcT[(g * 16 + j) * ld + r];

  for (int s = 0; s < 8; ++s) {
    // ---- stage: panel slice (its owners) + old panel rows (all groups) ----
    if (g == s) {
#pragma unroll
      for (int j = 0; j < 16; ++j) PanelBuf[j][r] = a[j];
    }
    if ((r >> 4) == s) {
      const int kk = r & 15;
#pragma unroll
      for (int j = 0; j < 16; ++j) ArowsBuf[kk][g * 16 + j] = a[j];
    }
    __syncthreads();

    // ---- phase 1: wave 0, 16 sequential pivots on the slice, in registers ----
    if (tid < 64) {
      float rA[16], rB[16], pj[16];
#pragma unroll
      for (int j = 0; j < 16; ++j) {
        rA[j] = PanelBuf[j][tid];
        rB[j] = PanelBuf[j][tid + 64];
      }
#pragma unroll
      for (int kk = 0; kk < 16; ++kk) {
        const int rp = s * 16 + kk;  // global pivot row
        const int lp = rp & 63;
        const bool hi = rp >= 64;
#pragma unroll
        for (int j = 0; j < 16; ++j) pj[j] = __shfl(hi ? rB[j] : rA[j], lp, 64);
        const float piv = 1.0f / pj[kk];
        const float tA = rA[kk], tB = rB[kk];
        const bool isA = (!hi) && (tid == lp);
        const bool isB = hi && (tid == lp);
#pragma unroll
        for (int j = 0; j < 16; ++j) {
          const float ps = pj[j] * piv;  // scaled pivot row value
          if (j == kk) {
            rA[kk] = isA ? piv : -tA * piv;  // column-k replacement (inverse col)
            rB[kk] = isB ? piv : -tB * piv;
          } else {
            rA[j] = isA ? ps : rA[j] - tA * ps;
            rB[j] = isB ? ps : rB[j] - tB * ps;
          }
        }
      }
#pragma unroll
      for (int j = 0; j < 16; ++j) {
        MBuf[j][tid] = rA[j];
        MBuf[j][tid + 64] = rB[j];
      }
    }
    __syncthreads();

    // ---- phase 2: apply E_panel ----
    float m[16];
#pragma unroll
    for (int j = 0; j < 16; ++j) m[j] = MBuf[j][r];  // M[r][kk], conflict-free
    if (g == s) {
      // panel columns are replaced by M
#pragma unroll
      for (int j = 0; j < 16; ++j) a[j] = m[j];
    } else {
      const bool inPanel = ((r >> 4) == s);
#pragma unroll
      for (int j = 0; j < 16; ++j) a[j] = inPanel ? 0.0f : a[j];
#pragma unroll
      for (int kk = 0; kk < 16; ++kk) {
        const float mk = m[kk];
        const float4 v0 = *(const float4*)&ArowsBuf[kk][g * 16 + 0];   // broadcast
        const float4 v1 = *(const float4*)&ArowsBuf[kk][g * 16 + 4];
        const float4 v2 = *(const float4*)&ArowsBuf[kk][g * 16 + 8];
        const float4 v3 = *(const float4*)&ArowsBuf[kk][g * 16 + 12];
        a[0] += mk * v0.x;   a[1] += mk * v0.y;   a[2] += mk * v0.z;   a[3] += mk * v0.w;
        a[4] += mk * v1.x;   a[5] += mk * v1.y;   a[6] += mk * v1.z;   a[7] += mk * v1.w;
        a[8] += mk * v2.x;   a[9] += mk * v2.y;   a[10] += mk * v2.z;  a[11] += mk * v2.w;
        a[12] += mk * v3.x;  a[13] += mk * v3.y;  a[14] += mk * v3.z;  a[15] += mk * v3.w;
      }
    }
    __syncthreads();
  }
#pragma unroll
  for (int j = 0; j < 16; ++j) dstT[(g * 16 + j) * 128 + r] = a[j];  // coalesced in r
}

// ---------- W = invA11 * A12 ; z1 = invA11 * c1   (A = E^T, c = C2^T) ----------
__global__ __launch_bounds__(256) void k_WZ(const float* __restrict__ E,
                                            const float* __restrict__ C2,
                                            const float* __restrict__ inv1T,
                                            float* __restrict__ W,
                                            float* __restrict__ z1) {
  const int gid = blockIdx.x * 256 + threadIdx.x;  // 32768 threads
  const int half = gid >> 14;
  const int idx = gid & 16383;
  const int i = idx >> 7;
  const int j = idx & 127;
  float s = 0.f;
  if (half == 0) {
    // A12[m][j] = E[128+j][m]
    for (int m = 0; m < 128; ++m) s += inv1T[m * 128 + i] * E[(128 + j) * 256 + m];
    W[i * 128 + j] = s;
  } else {
    // c1[m][o] = C2[o][m]   (j plays the role of o)
    for (int m = 0; m < 128; ++m) s += inv1T[m * 128 + i] * C2[j * 256 + m];
    z1[i * 128 + j] = s;
  }
}

// ---------- S^T = (A22 - A21 W)^T ; c2p = c2 - A21 z1 ----------
__global__ __launch_bounds__(256) void k_SC(const float* __restrict__ E,
                                            const float* __restrict__ C2,
                                            const float* __restrict__ W,
                                            const float* __restrict__ z1,
                                            float* __restrict__ STt,
                                            float* __restrict__ c2p) {
  const int gid = blockIdx.x * 256 + threadIdx.x;  // 32768 threads
  if (gid < 16384) {
    const int jj = gid >> 7;  // S column
    const int i = gid & 127;  // S row
    // A22[i][j] = E[128+j][128+i] ; A21[i][m] = E[m][128+i]
    float s = E[(128 + jj) * 256 + 128 + i];
    for (int m = 0; m < 128; ++m) s -= E[m * 256 + 128 + i] * W[m * 128 + jj];
    STt[jj * 128 + i] = s;  // store S transposed
  } else {
    const int idx = gid - 16384;
    const int i = idx >> 7;
    const int o = idx & 127;
    float s = C2[o * 256 + 128 + i];  // c2[i][o] = C2[o][128+i]
    for (int m = 0; m < 128; ++m) s -= E[m * 256 + 128 + i] * z1[m * 128 + o];
    c2p[i * 128 + o] = s;
  }
}

// ---------- g2 = invS * c2p ----------
__global__ __launch_bounds__(256) void k_G2(const float* __restrict__ inv2T,
                                            const float* __restrict__ c2p,
                                            float* __restrict__ g2) {
  const int gid = blockIdx.x * 256 + threadIdx.x;  // 16384
  const int i = gid >> 7;
  const int o = gid & 127;
  float s = 0.f;
  for (int m = 0; m < 128; ++m) s += inv2T[m * 128 + i] * c2p[m * 128 + o];
  g2[i * 128 + o] = s;
}

// ---------- g1 = z1 - W * g2 ----------
__global__ __launch_bounds__(256) void k_G1(const float* __restrict__ W,
                                            const float* __restrict__ z1,
                                            const float* __restrict__ g2,
                                            float* __restrict__ g1) {
  const int gid = blockIdx.x * 256 + threadIdx.x;  // 16384
  const int i = gid >> 7;
  const int o = gid & 127;
  float s = z1[i * 128 + o];
  for (int m = 0; m < 128; ++m) s -= W[i * 128 + m] * g2[m * 128 + o];
  g1[i * 128 + o] = s;
}

// ---------- R = [P | Q] (128 x 384) and y0 ----------
// P[o][l] = D21[o][l] + sum_k G[o][k] B1[k][l],  Q[o][i] = D22[o][i] + sum_k G[o][k] B2[k][i]
// y0[o] = sum_k G[o][k] xF[k] ;  G[o][k] = g1[k][o] (k<128) / g2[k-128][o]
__global__ __launch_bounds__(256) void k_R(const float* __restrict__ B1,
                                           const float* __restrict__ B2,
                                           const float* __restrict__ D21,
                                           const float* __restrict__ D22,
                                           const float* __restrict__ g1,
                                           const float* __restrict__ g2,
                                           const float* __restrict__ xF,
                                           float* __restrict__ R,
                                           float* __restrict__ y0) {
  const int gid = blockIdx.x * 256 + threadIdx.x;  // need 49280
  if (gid < 32768) {
    const int o = gid >> 8;
    const int l = gid & 255;
    float s = D21[o * 256 + l];
    for (int m = 0; m < 128; ++m) {
      s += g1[m * 128 + o] * B1[m * 256 + l];
      s += g2[m * 128 + o] * B1[(128 + m) * 256 + l];
    }
    R[o * 384 + l] = s;
  } else if (gid < 49152) {
    const int t = gid - 32768;
    const int o = t >> 7;
    const int i = t & 127;
    float s = D22[o * 128 + i];
    for (int m = 0; m < 128; ++m) {
      s += g1[m * 128 + o] * B2[m * 128 + i];
      s += g2[m * 128 + o] * B2[(128 + m) * 128 + i];
    }
    R[o * 384 + 256 + i] = s;
  } else if (gid < 49280) {
    const int o = gid - 49152;
    float s = 0.f;
    for (int m = 0; m < 128; ++m) {
      s += g1[m * 128 + o] * xF[m];
      s += g2[m * 128 + o] * xF[128 + m];
    }
    y0[o] = s;
  }
}

// ---------- vw[l][b] = cx[l] + D12[l,:]·u[b,:] ----------
__global__ __launch_bounds__(256) void k_du(const float* __restrict__ u,
                                            const float* __restrict__ D12,
                                            const float* __restrict__ cx,
                                            float* __restrict__ vw) {
  const int b = blockIdx.x * 256 + threadIdx.x;
  const int l0 = blockIdx.y * 16;
  float acc[16];
#pragma unroll
  for (int j = 0; j < 16; ++j) acc[j] = cx[l0 + j];
  for (int i = 0; i < 128; i += 4) {
    const float4 uv = *(const float4*)&u[b * 128 + i];
#pragma unroll
    for (int j = 0; j < 16; ++j) {
      acc[j] += D12[(l0 + j) * 128 + i + 0] * uv.x;
      acc[j] += D12[(l0 + j) * 128 + i + 1] * uv.y;
      acc[j] += D12[(l0 + j) * 128 + i + 2] * uv.z;
      acc[j] += D12[(l0 + j) * 128 + i + 3] * uv.w;
    }
  }
#pragma unroll
  for (int j = 0; j < 16; ++j) vw[(l0 + j) * NB + b] = acc[j];
}

// ---------- sequential 64-step scan chunk: compact loop, 1 wave/block ----------
// LDS history wl[k][t]: bank = t%32 -> 2-way alias (free). Single wave => no barriers,
// LDS ops are program-ordered within the wave. D11/rLam accesses wave-uniform.
__global__ __launch_bounds__(64) void k_scan(const float* __restrict__ D11,
                                             const float* __restrict__ rLam,
                                             float* __restrict__ vw, int c) {
  __shared__ float wl[64][64];
  const int t = threadIdx.x;
  const int b = blockIdx.x * 64 + t;
  const int l0 = c * 64;
  for (int li = 0; li < 64; ++li) {
    const int l = l0 + li;
    float v = vw[l * NB + b];
    const float* drow = D11 + l * 256 + l0;  // wave-uniform -> scalar loads
    float s0 = 0.f, s1 = 0.f, s2 = 0.f, s3 = 0.f;
    int k = 0;
    for (; k + 3 < li; k += 4) {
      s0 += drow[k + 0] * wl[k + 0][t];
      s1 += drow[k + 1] * wl[k + 1][t];
      s2 += drow[k + 2] * wl[k + 2][t];
      s3 += drow[k + 3] * wl[k + 3][t];
    }
    for (; k < li; ++k) s0 += drow[k] * wl[k][t];
    v += (s0 + s1) + (s2 + s3);
    const float w = tanhf(v * rLam[l]);
    wl[li][t] = w;
    vw[l * NB + b] = w;
  }
}

// ---------- cross-chunk rank-64 update: vw[l'][b] += D11[l', chunk]·w[chunk][b] ----------
__global__ __launch_bounds__(256) void k_upd(const float* __restrict__ D11,
                                             float* __restrict__ vw, int c) {
  const int b = blockIdx.x * 256 + threadIdx.x;
  const int lp0 = (c + 1) * 64 + blockIdx.y * 8;
  const int k0 = c * 64;
  float acc[8];
#pragma unroll
  for (int j = 0; j < 8; ++j) acc[j] = vw[(lp0 + j) * NB + b];
  for (int k = 0; k < 64; ++k) {
    const float wv = vw[(k0 + k) * NB + b];
#pragma unroll
    for (int j = 0; j < 8; ++j) acc[j] += D11[(lp0 + j) * 256 + k0 + k] * wv;
  }
#pragma unroll
  for (int j = 0; j < 8; ++j) vw[(lp0 + j) * NB + b] = acc[j];
}

// ---------- y[b][o] = y0[o] + sum_l R[o][l] w[l][b] + sum_i R[o][256+i] u[b][i] ----------
__global__ __launch_bounds__(256) void k_y(const float* __restrict__ u,
                                           const float* __restrict__ vw,
                                           const float* __restrict__ R,
                                           const float* __restrict__ y0,
                                           float* __restrict__ y) {
  const int b = blockIdx.x * 256 + threadIdx.x;
  const int o0 = blockIdx.y * 16;
  float acc[16];
#pragma unroll
  for (int j = 0; j < 16; ++j) acc[j] = y0[o0 + j];
  for (int l = 0; l < 256; ++l) {
    const float wv = vw[l * NB + b];
#pragma unroll
    for (int j = 0; j < 16; ++j) acc[j] += R[(o0 + j) * 384 + l] * wv;
  }
  for (int i = 0; i < 128; i += 4) {
    const float4 uv = *(const float4*)&u[b * 128 + i];
#pragma unroll
    for (int j = 0; j < 16; ++j) {
      acc[j] += R[(o0 + j) * 384 + 256 + i + 0] * uv.x;
      acc[j] += R[(o0 + j) * 384 + 256 + i + 1] * uv.y;
      acc[j] += R[(o0 + j) * 384 + 256 + i + 2] * uv.z;
      acc[j] += R[(o0 + j) * 384 + 256 + i + 3] * uv.w;
    }
  }
#pragma unroll
  for (int j = 0; j < 16; j += 4) {
    *(float4*)&y[b * 128 + o0 + j] = make_float4(acc[j], acc[j + 1], acc[j + 2], acc[j + 3]);
  }
}

extern "C" void kernel_launch(void* const* d_in, const int* in_sizes, int n_in,
                              void* d_out, int out_size, void* d_ws, size_t ws_size,
                              hipStream_t stream) {
  const float* u   = (const float*)d_in[0];   // (8192,1,128)
  const float* x   = (const float*)d_in[1];   // (1,1,256)
  const float* Fm  = (const float*)d_in[2];   // (256,256)
  const float* B1  = (const float*)d_in[3];   // (256,256)
  const float* B2  = (const float*)d_in[4];   // (256,128)
  const float* C1  = (const float*)d_in[5];   // (256,256)
  const float* C2  = (const float*)d_in[6];   // (128,256)
  const float* D11 = (const float*)d_in[7];   // (256,256) strictly lower
  const float* D12 = (const float*)d_in[8];   // (256,128)
  const float* D21 = (const float*)d_in[9];   // (128,256)
  const float* D22 = (const float*)d_in[10];  // (128,128)
  const float* E   = (const float*)d_in[11];  // (256,256)
  const float* Lam = (const float*)d_in[12];  // (256,)
  float* y = (float*)d_out;                   // (8192,1,128) fp32

  float* F = (float*)d_ws;                    // ~8.7 MB used
  float* vw    = F;                            // 256*8192
  float* SMb   = F + 256 * NB;
  float* inv1T = SMb;                          // 16384
  float* Wm    = SMb + 16384;
  float* z1    = SMb + 32768;
  float* STt   = SMb + 49152;
  float* c2p   = SMb + 65536;
  float* inv2T = SMb + 81920;
  float* g2    = SMb + 98304;
  float* g1    = SMb + 114688;
  float* Rm    = SMb + 131072;                 // 128*384
  float* y0v   = SMb + 180224;                 // 128
  float* cx    = SMb + 180352;                 // 256
  float* xF    = SMb + 180608;                 // 256
  float* rLam  = SMb + 180864;                 // 256

  // small precompute + Schur solve chain for G = C2 * inv(E)  (E^T G^T = C2^T)
  k_prep<<<1, 256, 0, stream>>>(x, C1, Fm, Lam, cx, xF, rLam);
  k_inv<<<1, 1024, 0, stream>>>(E, 256, inv1T);          // inv(A11), A = E^T
  k_WZ<<<128, 256, 0, stream>>>(E, C2, inv1T, Wm, z1);
  k_SC<<<128, 256, 0, stream>>>(E, C2, Wm, z1, STt, c2p);
  k_inv<<<1, 1024, 0, stream>>>(STt, 128, inv2T);        // inv(S)
  k_G2<<<64, 256, 0, stream>>>(inv2T, c2p, g2);
  k_G1<<<64, 256, 0, stream>>>(Wm, z1, g2, g1);
  k_R<<<193, 256, 0, stream>>>(B1, B2, D21, D22, g1, g2, xF, Rm, y0v);

  // batch pipeline: v-init, chunked scan, output GEMM
  k_du<<<dim3(32, 16), 256, 0, stream>>>(u, D12, cx, vw);
  for (int c = 0; c < 4; ++c) {
    k_scan<<<128, 64, 0, stream>>>(D11, rLam, vw, c);
    if (c < 3) {
      const int tiles = (256 - (c + 1) * 64) / 8;
      k_upd<<<dim3(32, tiles), 256, 0, stream>>>(D11, vw, c);
    }
  }
  k_y<<<dim3(32, 8), 256, 0, stream>>>(u, vw, Rm, y0v, y);
}

// Round 4
// 586.148 us; speedup vs baseline: 1.0702x; 1.0702x over previous
//
#include <hip/hip_runtime.h>
#include <utility>

// Problem constants
// DIM_IN=128, DIM_OUT=128, DIM_X=256, L=256, BATCH=8192, fp32 everywhere.
#define NB 8192

// fast tanh: 1 - 2/(exp(2x)+1). Correct limits: x->+inf e=inf -> 1; x->-inf e=0 -> -1.
__device__ __forceinline__ float fast_tanh(float x) {
  const float e = __expf(2.0f * x);
  return 1.0f - 2.0f / (e + 1.0f);
}

// ---------- prep: cx[l] = C1[l,:]·x ; xF[k] = Fm[k,:]·x ; rLam = 1/Lam ----------
__global__ __launch_bounds__(256) void k_prep(const float* __restrict__ x,
                                              const float* __restrict__ C1,
                                              const float* __restrict__ Fm,
                                              const float* __restrict__ Lam,
                                              float* __restrict__ cx,
                                              float* __restrict__ xF,
                                              float* __restrict__ rLam) {
  const int t = threadIdx.x;  // 0..255
  float s1 = 0.f, s2 = 0.f;
  for (int i = 0; i < 256; ++i) {
    const float xi = x[i];
    s1 += C1[t * 256 + i] * xi;
    s2 += Fm[t * 256 + i] * xi;
  }
  cx[t] = s1;
  xF[t] = s2;
  rLam[t] = 1.0f / Lam[t];
}

// ---------- blocked-panel in-place Gauss-Jordan inverse of 128x128, no pivoting ----
// (unchanged from R3 — no longer in top-5)
__global__ __launch_bounds__(1024) void k_inv(const float* __restrict__ srcT, int ld,
                                              float* __restrict__ dstT) {
  __shared__ float PanelBuf[16][128];
  __shared__ float MBuf[16][128];
  __shared__ float ArowsBuf[16][128];
  const int tid = threadIdx.x;
  const int r = tid & 127;
  const int g = tid >> 7;
  float a[16];
#pragma unroll
  for (int j = 0; j < 16; ++j) a[j] = srcT[(g * 16 + j) * ld + r];

  for (int s = 0; s < 8; ++s) {
    if (g == s) {
#pragma unroll
      for (int j = 0; j < 16; ++j) PanelBuf[j][r] = a[j];
    }
    if ((r >> 4) == s) {
      const int kk = r & 15;
#pragma unroll
      for (int j = 0; j < 16; ++j) ArowsBuf[kk][g * 16 + j] = a[j];
    }
    __syncthreads();

    if (tid < 64) {
      float rA[16], rB[16], pj[16];
#pragma unroll
      for (int j = 0; j < 16; ++j) {
        rA[j] = PanelBuf[j][tid];
        rB[j] = PanelBuf[j][tid + 64];
      }
#pragma unroll
      for (int kk = 0; kk < 16; ++kk) {
        const int rp = s * 16 + kk;
        const int lp = rp & 63;
        const bool hi = rp >= 64;
#pragma unroll
        for (int j = 0; j < 16; ++j) pj[j] = __shfl(hi ? rB[j] : rA[j], lp, 64);
        const float piv = 1.0f / pj[kk];
        const float tA = rA[kk], tB = rB[kk];
        const bool isA = (!hi) && (tid == lp);
        const bool isB = hi && (tid == lp);
#pragma unroll
        for (int j = 0; j < 16; ++j) {
          const float ps = pj[j] * piv;
          if (j == kk) {
            rA[kk] = isA ? piv : -tA * piv;
            rB[kk] = isB ? piv : -tB * piv;
          } else {
            rA[j] = isA ? ps : rA[j] - tA * ps;
            rB[j] = isB ? ps : rB[j] - tB * ps;
          }
        }
      }
#pragma unroll
      for (int j = 0; j < 16; ++j) {
        MBuf[j][tid] = rA[j];
        MBuf[j][tid + 64] = rB[j];
      }
    }
    __syncthreads();

    float m[16];
#pragma unroll
    for (int j = 0; j < 16; ++j) m[j] = MBuf[j][r];
    if (g == s) {
#pragma unroll
      for (int j = 0; j < 16; ++j) a[j] = m[j];
    } else {
      const bool inPanel = ((r >> 4) == s);
#pragma unroll
      for (int j = 0; j < 16; ++j) a[j] = inPanel ? 0.0f : a[j];
#pragma unroll
      for (int kk = 0; kk < 16; ++kk) {
        const float mk = m[kk];
        const float4 v0 = *(const float4*)&ArowsBuf[kk][g * 16 + 0];
        const float4 v1 = *(const float4*)&ArowsBuf[kk][g * 16 + 4];
        const float4 v2 = *(const float4*)&ArowsBuf[kk][g * 16 + 8];
        const float4 v3 = *(const float4*)&ArowsBuf[kk][g * 16 + 12];
        a[0] += mk * v0.x;   a[1] += mk * v0.y;   a[2] += mk * v0.z;   a[3] += mk * v0.w;
        a[4] += mk * v1.x;   a[5] += mk * v1.y;   a[6] += mk * v1.z;   a[7] += mk * v1.w;
        a[8] += mk * v2.x;   a[9] += mk * v2.y;   a[10] += mk * v2.z;  a[11] += mk * v2.w;
        a[12] += mk * v3.x;  a[13] += mk * v3.y;  a[14] += mk * v3.z;  a[15] += mk * v3.w;
      }
    }
    __syncthreads();
  }
#pragma unroll
  for (int j = 0; j < 16; ++j) dstT[(g * 16 + j) * 128 + r] = a[j];
}

// ---------- W = invA11 * A12 ; z1 = invA11 * c1   (A = E^T, c = C2^T) ----------
// lane = i (coalesced inv1T), wave-uniform = j (scalar E/C2 loads)
__global__ __launch_bounds__(256) void k_WZ(const float* __restrict__ E,
                                            const float* __restrict__ C2,
                                            const float* __restrict__ inv1T,
                                            float* __restrict__ W,
                                            float* __restrict__ z1) {
  const int gid = blockIdx.x * 256 + threadIdx.x;  // 32768 threads
  const int half = gid >> 14;
  const int idx = gid & 16383;
  const int j = idx >> 7;   // wave-uniform
  const int i = idx & 127;  // lane
  float s = 0.f;
  if (half == 0) {
    for (int m = 0; m < 128; ++m) s += inv1T[m * 128 + i] * E[(128 + j) * 256 + m];
    W[i * 128 + j] = s;
  } else {
    for (int m = 0; m < 128; ++m) s += inv1T[m * 128 + i] * C2[j * 256 + m];
    z1[i * 128 + j] = s;
  }
}

// ---------- S^T = (A22 - A21 W)^T ; c2p = c2 - A21 z1 ----------
__global__ __launch_bounds__(256) void k_SC(const float* __restrict__ E,
                                            const float* __restrict__ C2,
                                            const float* __restrict__ W,
                                            const float* __restrict__ z1,
                                            float* __restrict__ STt,
                                            float* __restrict__ c2p) {
  const int gid = blockIdx.x * 256 + threadIdx.x;  // 32768 threads
  if (gid < 16384) {
    const int jj = gid >> 7;  // wave-uniform: S column
    const int i = gid & 127;  // lane: S row
    float s = E[(128 + jj) * 256 + 128 + i];
    for (int m = 0; m < 128; ++m) s -= E[m * 256 + 128 + i] * W[m * 128 + jj];
    STt[jj * 128 + i] = s;  // coalesced store
  } else {
    const int idx = gid - 16384;
    const int i = idx >> 7;  // wave-uniform
    const int o = idx & 127; // lane
    float s = C2[o * 256 + 128 + i];
    for (int m = 0; m < 128; ++m) s -= E[m * 256 + 128 + i] * z1[m * 128 + o];
    c2p[i * 128 + o] = s;  // coalesced store
  }
}

// ---------- g2 = invS * c2p ----------
__global__ __launch_bounds__(256) void k_G2(const float* __restrict__ inv2T,
                                            const float* __restrict__ c2p,
                                            float* __restrict__ g2) {
  const int gid = blockIdx.x * 256 + threadIdx.x;  // 16384
  const int i = gid >> 7;   // wave-uniform
  const int o = gid & 127;  // lane
  float s = 0.f;
  for (int m = 0; m < 128; ++m) s += inv2T[m * 128 + i] * c2p[m * 128 + o];
  g2[i * 128 + o] = s;
}

// ---------- g1 = z1 - W * g2 ----------
__global__ __launch_bounds__(256) void k_G1(const float* __restrict__ W,
                                            const float* __restrict__ z1,
                                            const float* __restrict__ g2,
                                            float* __restrict__ g1) {
  const int gid = blockIdx.x * 256 + threadIdx.x;  // 16384
  const int i = gid >> 7;   // wave-uniform
  const int o = gid & 127;  // lane
  float s = z1[i * 128 + o];
  for (int m = 0; m < 128; ++m) s -= W[i * 128 + m] * g2[m * 128 + o];
  g1[i * 128 + o] = s;
}

// ---------- R = [P | Q] (128 x 384) and y0 ----------
__global__ __launch_bounds__(256) void k_R(const float* __restrict__ B1,
                                           const float* __restrict__ B2,
                                           const float* __restrict__ D21,
                                           const float* __restrict__ D22,
                                           const float* __restrict__ g1,
                                           const float* __restrict__ g2,
                                           const float* __restrict__ xF,
                                           float* __restrict__ R,
                                           float* __restrict__ y0) {
  const int gid = blockIdx.x * 256 + threadIdx.x;  // need 49280
  if (gid < 32768) {
    const int o = gid >> 8;   // wave-uniform
    const int l = gid & 255;  // lane
    float s = D21[o * 256 + l];
    for (int m = 0; m < 128; ++m) {
      s += g1[m * 128 + o] * B1[m * 256 + l];
      s += g2[m * 128 + o] * B1[(128 + m) * 256 + l];
    }
    R[o * 384 + l] = s;
  } else if (gid < 49152) {
    const int t = gid - 32768;
    const int o = t >> 7;    // wave-uniform
    const int i = t & 127;   // lane
    float s = D22[o * 128 + i];
    for (int m = 0; m < 128; ++m) {
      s += g1[m * 128 + o] * B2[m * 128 + i];
      s += g2[m * 128 + o] * B2[(128 + m) * 128 + i];
    }
    R[o * 384 + 256 + i] = s;
  } else if (gid < 49280) {
    const int o = gid - 49152;
    float s = 0.f;
    for (int m = 0; m < 128; ++m) {
      s += g1[m * 128 + o] * xF[m];
      s += g2[m * 128 + o] * xF[128 + m];
    }
    y0[o] = s;
  }
}

// ---------- vw[l][b] = cx[l] + D12[l,:]·u[b,:]  AND  vw[256+i][b] = u[b][i] ----------
// y-block yj handles l = 16yj..16yj+15 and transposes u columns 8yj..8yj+7 (values it
// already loads for the dot product) into vw rows 256+8yj..256+8yj+7.
__global__ __launch_bounds__(256) void k_du(const float* __restrict__ u,
                                            const float* __restrict__ D12,
                                            const float* __restrict__ cx,
                                            float* __restrict__ vw) {
  const int b = blockIdx.x * 256 + threadIdx.x;
  const int yj = blockIdx.y;
  const int l0 = yj * 16;
  float acc[16];
  float u8[8];
#pragma unroll
  for (int j = 0; j < 16; ++j) acc[j] = cx[l0 + j];
#pragma unroll
  for (int i = 0; i < 128; i += 4) {
    const float4 uv = *(const float4*)&u[b * 128 + i];
    if (i == yj * 8) { u8[0] = uv.x; u8[1] = uv.y; u8[2] = uv.z; u8[3] = uv.w; }
    if (i == yj * 8 + 4) { u8[4] = uv.x; u8[5] = uv.y; u8[6] = uv.z; u8[7] = uv.w; }
#pragma unroll
    for (int j = 0; j < 16; ++j) {
      acc[j] += D12[(l0 + j) * 128 + i + 0] * uv.x;
      acc[j] += D12[(l0 + j) * 128 + i + 1] * uv.y;
      acc[j] += D12[(l0 + j) * 128 + i + 2] * uv.z;
      acc[j] += D12[(l0 + j) * 128 + i + 3] * uv.w;
    }
  }
#pragma unroll
  for (int j = 0; j < 16; ++j) vw[(l0 + j) * NB + b] = acc[j];
#pragma unroll
  for (int q = 0; q < 8; ++q) vw[(256 + yj * 8 + q) * NB + b] = u8[q];
}

// ---------- sequential 64-step scan chunk, 1 wave/block ----------
// v-inits prefetched into the LDS history array (pipelined, unrolled) so the serial
// loop touches only LDS + scalar D11 loads — no global latency on the critical path.
__global__ __launch_bounds__(64) void k_scan(const float* __restrict__ D11,
                                             const float* __restrict__ rLam,
                                             float* __restrict__ vw, int c) {
  __shared__ float wl[64][64];  // [k][t]: 2-way bank alias (free); doubles as v-init buf
  const int t = threadIdx.x;
  const int b = blockIdx.x * 64 + t;
  const int l0 = c * 64;
#pragma unroll
  for (int li = 0; li < 64; ++li) wl[li][t] = vw[(l0 + li) * NB + b];  // pipelined
  // single wave: LDS ops are program-ordered; no barrier needed
  for (int li = 0; li < 64; ++li) {
    const int l = l0 + li;
    const float* drow = D11 + l * 256 + l0;  // wave-uniform -> scalar loads
    float s0 = 0.f, s1 = 0.f, s2 = 0.f, s3 = 0.f;
    int k = 0;
    for (; k + 3 < li; k += 4) {
      s0 += drow[k + 0] * wl[k + 0][t];
      s1 += drow[k + 1] * wl[k + 1][t];
      s2 += drow[k + 2] * wl[k + 2][t];
      s3 += drow[k + 3] * wl[k + 3][t];
    }
    for (; k < li; ++k) s0 += drow[k] * wl[k][t];
    const float v = wl[li][t] + (s0 + s1) + (s2 + s3);
    const float w = fast_tanh(v * rLam[l]);
    wl[li][t] = w;
    vw[l * NB + b] = w;  // fire-and-forget
  }
}

// ---------- cross-chunk rank-64 update: vw[l'][b] += D11[l', chunk]·w[chunk][b] ----------
// float4 over b: per k-iter 1 vector load feeds 32 FMAs.
__global__ __launch_bounds__(256) void k_upd(const float* __restrict__ D11,
                                             float* __restrict__ vw, int c) {
  float4* vw4 = (float4*)vw;
  const int b4 = blockIdx.x * 256 + threadIdx.x;  // float4 index, 2048 per row
  const int lp0 = (c + 1) * 64 + blockIdx.y * 8;
  const int k0 = c * 64;
  float4 acc[8];
#pragma unroll
  for (int j = 0; j < 8; ++j) acc[j] = vw4[(lp0 + j) * 2048 + b4];
  for (int k = 0; k < 64; ++k) {
    const float4 wv = vw4[(k0 + k) * 2048 + b4];
#pragma unroll
    for (int j = 0; j < 8; ++j) {
      const float d = D11[(lp0 + j) * 256 + k0 + k];  // wave-uniform scalar
      acc[j].x += d * wv.x;
      acc[j].y += d * wv.y;
      acc[j].z += d * wv.z;
      acc[j].w += d * wv.w;
    }
  }
#pragma unroll
  for (int j = 0; j < 8; ++j) vw4[(lp0 + j) * 2048 + b4] = acc[j];
}

// ---------- y[b][o] = y0[o] + sum_{k<384} R[o][k] vw[k][b] ----------
// R o-tile (4 rows, 6 KB) staged in LDS; per-thread 4b(float4) x 4o register tile.
// XCD swizzle: bid&7 selects b-tile so each 1.5 MB vw slice stays in one XCD's L2.
__global__ __launch_bounds__(256) void k_y(const float* __restrict__ vw,
                                           const float* __restrict__ R,
                                           const float* __restrict__ y0,
                                           float* __restrict__ y) {
  __shared__ float Rl[1536];  // rows o0..o0+3 of R, flat
  const int tid = threadIdx.x;
  const int bid = blockIdx.x;       // 256 blocks
  const int gx = bid & 7;           // b-tile (XCD-aligned)
  const int gy = bid >> 3;          // o-tile, 0..31
  const int o0 = gy * 4;
#pragma unroll
  for (int q = 0; q < 6; ++q) Rl[q * 256 + tid] = R[o0 * 384 + q * 256 + tid];
  __syncthreads();

  const float4* vw4 = (const float4*)vw;
  const int b4 = gx * 256 + tid;    // float4 index into each 8192-wide row
  float acc[4][4];
#pragma unroll
  for (int j = 0; j < 4; ++j) {
    const float y0j = y0[o0 + j];
#pragma unroll
    for (int bi = 0; bi < 4; ++bi) acc[bi][j] = y0j;
  }
#pragma unroll 4
  for (int k = 0; k < 384; k += 4) {
    const float4 w0 = vw4[(k + 0) * 2048 + b4];
    const float4 w1 = vw4[(k + 1) * 2048 + b4];
    const float4 w2 = vw4[(k + 2) * 2048 + b4];
    const float4 w3 = vw4[(k + 3) * 2048 + b4];
#pragma unroll
    for (int j = 0; j < 4; ++j) {
      const float4 r = *(const float4*)&Rl[j * 384 + k];  // LDS broadcast, 16B aligned
      acc[0][j] += r.x * w0.x + r.y * w1.x + r.z * w2.x + r.w * w3.x;
      acc[1][j] += r.x * w0.y + r.y * w1.y + r.z * w2.y + r.w * w3.y;
      acc[2][j] += r.x * w0.z + r.y * w1.z + r.z * w2.z + r.w * w3.z;
      acc[3][j] += r.x * w0.w + r.y * w1.w + r.z * w2.w + r.w * w3.w;
    }
  }
  const int b0 = b4 * 4;
#pragma unroll
  for (int bi = 0; bi < 4; ++bi) {
    *(float4*)&y[(b0 + bi) * 128 + o0] =
        make_float4(acc[bi][0], acc[bi][1], acc[bi][2], acc[bi][3]);
  }
}

extern "C" void kernel_launch(void* const* d_in, const int* in_sizes, int n_in,
                              void* d_out, int out_size, void* d_ws, size_t ws_size,
                              hipStream_t stream) {
  const float* u   = (const float*)d_in[0];   // (8192,1,128)
  const float* x   = (const float*)d_in[1];   // (1,1,256)
  const float* Fm  = (const float*)d_in[2];   // (256,256)
  const float* B1  = (const float*)d_in[3];   // (256,256)
  const float* B2  = (const float*)d_in[4];   // (256,128)
  const float* C1  = (const float*)d_in[5];   // (256,256)
  const float* C2  = (const float*)d_in[6];   // (128,256)
  const float* D11 = (const float*)d_in[7];   // (256,256) strictly lower
  const float* D12 = (const float*)d_in[8];   // (256,128)
  const float* D21 = (const float*)d_in[9];   // (128,256)
  const float* D22 = (const float*)d_in[10];  // (128,128)
  const float* E   = (const float*)d_in[11];  // (256,256)
  const float* Lam = (const float*)d_in[12];  // (256,)
  float* y = (float*)d_out;                   // (8192,1,128) fp32

  float* F = (float*)d_ws;                    // ~13.3 MB used
  float* vw    = F;                            // 384*8192 (rows 256..383 = u^T)
  float* SMb   = F + 384 * NB;
  float* inv1T = SMb;                          // 16384
  float* Wm    = SMb + 16384;
  float* z1    = SMb + 32768;
  float* STt   = SMb + 49152;
  float* c2p   = SMb + 65536;
  float* inv2T = SMb + 81920;
  float* g2    = SMb + 98304;
  float* g1    = SMb + 114688;
  float* Rm    = SMb + 131072;                 // 128*384
  float* y0v   = SMb + 180224;                 // 128
  float* cx    = SMb + 180352;                 // 256
  float* xF    = SMb + 180608;                 // 256
  float* rLam  = SMb + 180864;                 // 256

  // small precompute + Schur solve chain for G = C2 * inv(E)  (E^T G^T = C2^T)
  k_prep<<<1, 256, 0, stream>>>(x, C1, Fm, Lam, cx, xF, rLam);
  k_inv<<<1, 1024, 0, stream>>>(E, 256, inv1T);          // inv(A11), A = E^T
  k_WZ<<<128, 256, 0, stream>>>(E, C2, inv1T, Wm, z1);
  k_SC<<<128, 256, 0, stream>>>(E, C2, Wm, z1, STt, c2p);
  k_inv<<<1, 1024, 0, stream>>>(STt, 128, inv2T);        // inv(S)
  k_G2<<<64, 256, 0, stream>>>(inv2T, c2p, g2);
  k_G1<<<64, 256, 0, stream>>>(Wm, z1, g2, g1);
  k_R<<<193, 256, 0, stream>>>(B1, B2, D21, D22, g1, g2, xF, Rm, y0v);

  // batch pipeline: v-init (+u transpose), chunked scan, output GEMM
  k_du<<<dim3(32, 16), 256, 0, stream>>>(u, D12, cx, vw);
  for (int c = 0; c < 4; ++c) {
    k_scan<<<128, 64, 0, stream>>>(D11, rLam, vw, c);
    if (c < 3) {
      const int tiles = (256 - (c + 1) * 64) / 8;
      k_upd<<<dim3(8, tiles), 256, 0, stream>>>(D11, vw, c);
    }
  }
  k_y<<<256, 256, 0, stream>>>(vw, Rm, y0v, y);
}

// Round 5
// 498.039 us; speedup vs baseline: 1.2596x; 1.1769x over previous
//
#include <hip/hip_runtime.h>
#include <utility>

// Problem constants
// DIM_IN=128, DIM_OUT=128, DIM_X=256, L=256, BATCH=8192, fp32 everywhere.
#define NB 8192

// ---------- static_for helper (compile-time register indices) ----------
template <typename F, size_t... I>
__device__ __forceinline__ void sfor_impl(F&& f, std::index_sequence<I...>) {
  (f(std::integral_constant<int, (int)I>{}), ...);
}
template <int N, typename F>
__device__ __forceinline__ void sfor(F&& f) {
  sfor_impl((F&&)f, std::make_index_sequence<N>{});
}

// packed-column-triangle offset: column li holds D[l2][li], l2=li+1..63, padded to x4
constexpr int coff(int li) {
  int o = 0;
  for (int j = 0; j < li; ++j) o += ((63 - j) + 3) & ~3;
  return o;
}
#define CPACK_STRIDE 2176  // > coff(63), float4-aligned

// fast tanh: 1 - 2/(exp(2x)+1). Correct limits at +/-inf.
__device__ __forceinline__ float fast_tanh(float x) {
  const float e = __expf(2.0f * x);
  return 1.0f - 2.0f / (e + 1.0f);
}

// ---------- prep: cx[l] = C1[l,:]·x ; xF[k] = Fm[k,:]·x ; rLam = 1/Lam ----------
__global__ __launch_bounds__(256) void k_prep(const float* __restrict__ x,
                                              const float* __restrict__ C1,
                                              const float* __restrict__ Fm,
                                              const float* __restrict__ Lam,
                                              float* __restrict__ cx,
                                              float* __restrict__ xF,
                                              float* __restrict__ rLam) {
  const int t = threadIdx.x;  // 0..255
  float s1 = 0.f, s2 = 0.f;
  for (int i = 0; i < 256; ++i) {
    const float xi = x[i];
    s1 += C1[t * 256 + i] * xi;
    s2 += Fm[t * 256 + i] * xi;
  }
  cx[t] = s1;
  xF[t] = s2;
  rLam[t] = 1.0f / Lam[t];
}

// ---------- pack D11 chunk-triangles column-major for the register scan ----------
// cpack[c][coff(li) + (l2-li-1)] = D11[c*64+l2][c*64+li]
__global__ __launch_bounds__(64) void k_pack(const float* __restrict__ D11,
                                             float* __restrict__ cpack) {
  const int c = blockIdx.x;
  const int t = threadIdx.x;
  int off = 0;
  for (int li = 0; li < 63; ++li) {
    if (t < 63 - li)
      cpack[c * CPACK_STRIDE + off + t] = D11[(c * 64 + li + 1 + t) * 256 + (c * 64 + li)];
    off += ((63 - li) + 3) & ~3;
  }
}

// ---------- blocked-panel in-place Gauss-Jordan inverse of 128x128, no pivoting ----
// Identity used: in-place GJ of the panel slice == [ D^-1 (pivot rows) ; -A_np D^-1 ].
// Phase 1a: 16 lanes invert the 16x16 pivot block D in registers (shfl-16).
// Phase 1b: all 1024 threads build M = [-A_np D^-1 ; D^-1] (parallel GEMM).
// Phase 2: rank-16 update with OLD panel rows (ArowsBuf, padded to 132 vs conflicts).
__global__ __launch_bounds__(1024) void k_inv(const float* __restrict__ srcT, int ld,
                                              float* __restrict__ dstT) {
  __shared__ float PanelBuf[16][128];  // [j][r] original panel slice
  __shared__ float MBuf[16][128];      // [j][r] panel transform M
  __shared__ float ArowsBuf[16][132];  // [kk][col] old panel-row values (padded)
  __shared__ float invD[16 * 17];      // [k][j] inverse of pivot block (padded)
  const int tid = threadIdx.x;
  const int r = tid & 127;
  const int g = tid >> 7;
  float a[16];
#pragma unroll
  for (int j = 0; j < 16; ++j) a[j] = srcT[(g * 16 + j) * ld + r];

  for (int s = 0; s < 8; ++s) {
    // stage panel slice + old panel rows
    if (g == s) {
#pragma unroll
      for (int j = 0; j < 16; ++j) PanelBuf[j][r] = a[j];
    }
    if ((r >> 4) == s) {
      const int kk = r & 15;
#pragma unroll
      for (int j = 0; j < 16; ++j) ArowsBuf[kk][g * 16 + j] = a[j];
    }
    __syncthreads();

    // ---- 1a: invert 16x16 pivot block, 16 lanes, registers ----
    if (tid < 16) {
      float q[16];
#pragma unroll
      for (int j = 0; j < 16; ++j) q[j] = PanelBuf[j][s * 16 + tid];
#pragma unroll
      for (int kk = 0; kk < 16; ++kk) {
        float ps[16];
#pragma unroll
        for (int j = 0; j < 16; ++j) ps[j] = __shfl(q[j], kk, 16);
        const float piv = 1.0f / ps[kk];
#pragma unroll
        for (int j = 0; j < 16; ++j) ps[j] = (j == kk) ? piv : ps[j] * piv;
        const bool isP = (tid == kk);
        const float te = isP ? -1.0f : q[kk];
#pragma unroll
        for (int j = 0; j < 16; ++j) {
          const float base = (isP || j == kk) ? 0.0f : q[j];
          q[j] = base - te * ps[j];
        }
      }
#pragma unroll
      for (int j = 0; j < 16; ++j) invD[tid * 17 + j] = q[j];
    }
    __syncthreads();

    // ---- 1b: M[r][j] ----
    {
      const int jA = 2 * g, jB = 2 * g + 1;
      float mA, mB;
      if ((r >> 4) == s) {
        const int rr = r & 15;
        mA = invD[rr * 17 + jA];
        mB = invD[rr * 17 + jB];
      } else {
        mA = 0.f;
        mB = 0.f;
#pragma unroll
        for (int k = 0; k < 16; ++k) {
          const float ar = PanelBuf[k][r];
          mA -= ar * invD[k * 17 + jA];
          mB -= ar * invD[k * 17 + jB];
        }
      }
      MBuf[jA][r] = mA;
      MBuf[jB][r] = mB;
    }
    __syncthreads();

    // ---- phase 2: apply E_panel ----
    float m[16];
#pragma unroll
    for (int j = 0; j < 16; ++j) m[j] = MBuf[j][r];
    if (g == s) {
#pragma unroll
      for (int j = 0; j < 16; ++j) a[j] = m[j];
    } else {
      const bool inPanel = ((r >> 4) == s);
#pragma unroll
      for (int j = 0; j < 16; ++j) a[j] = inPanel ? 0.0f : a[j];
#pragma unroll
      for (int kk = 0; kk < 16; ++kk) {
        const float mk = m[kk];
        const float4 v0 = *(const float4*)&ArowsBuf[kk][g * 16 + 0];
        const float4 v1 = *(const float4*)&ArowsBuf[kk][g * 16 + 4];
        const float4 v2 = *(const float4*)&ArowsBuf[kk][g * 16 + 8];
        const float4 v3 = *(const float4*)&ArowsBuf[kk][g * 16 + 12];
        a[0] += mk * v0.x;   a[1] += mk * v0.y;   a[2] += mk * v0.z;   a[3] += mk * v0.w;
        a[4] += mk * v1.x;   a[5] += mk * v1.y;   a[6] += mk * v1.z;   a[7] += mk * v1.w;
        a[8] += mk * v2.x;   a[9] += mk * v2.y;   a[10] += mk * v2.z;  a[11] += mk * v2.w;
        a[12] += mk * v3.x;  a[13] += mk * v3.y;  a[14] += mk * v3.z;  a[15] += mk * v3.w;
      }
    }
    __syncthreads();
  }
#pragma unroll
  for (int j = 0; j < 16; ++j) dstT[(g * 16 + j) * 128 + r] = a[j];  // coalesced in r
}

// ---------- W = invA11 * A12 ; z1 = invA11 * c1   (A = E^T, c = C2^T) ----------
__global__ __launch_bounds__(256) void k_WZ(const float* __restrict__ E,
                                            const float* __restrict__ C2,
                                            const float* __restrict__ inv1T,
                                            float* __restrict__ W,
                                            float* __restrict__ z1) {
  const int gid = blockIdx.x * 256 + threadIdx.x;  // 32768 threads
  const int half = gid >> 14;
  const int idx = gid & 16383;
  const int j = idx >> 7;   // wave-uniform
  const int i = idx & 127;  // lane
  float s = 0.f;
  if (half == 0) {
    for (int m = 0; m < 128; ++m) s += inv1T[m * 128 + i] * E[(128 + j) * 256 + m];
    W[i * 128 + j] = s;
  } else {
    for (int m = 0; m < 128; ++m) s += inv1T[m * 128 + i] * C2[j * 256 + m];
    z1[i * 128 + j] = s;
  }
}

// ---------- S^T = (A22 - A21 W)^T ; c2p = c2 - A21 z1 ----------
__global__ __launch_bounds__(256) void k_SC(const float* __restrict__ E,
                                            const float* __restrict__ C2,
                                            const float* __restrict__ W,
                                            const float* __restrict__ z1,
                                            float* __restrict__ STt,
                                            float* __restrict__ c2p) {
  const int gid = blockIdx.x * 256 + threadIdx.x;  // 32768 threads
  if (gid < 16384) {
    const int jj = gid >> 7;  // wave-uniform: S column
    const int i = gid & 127;  // lane: S row
    float s = E[(128 + jj) * 256 + 128 + i];
    for (int m = 0; m < 128; ++m) s -= E[m * 256 + 128 + i] * W[m * 128 + jj];
    STt[jj * 128 + i] = s;
  } else {
    const int idx = gid - 16384;
    const int i = idx >> 7;   // wave-uniform
    const int o = idx & 127;  // lane
    float s = C2[o * 256 + 128 + i];
    for (int m = 0; m < 128; ++m) s -= E[m * 256 + 128 + i] * z1[m * 128 + o];
    c2p[i * 128 + o] = s;
  }
}

// ---------- g2 = invS * c2p ----------
__global__ __launch_bounds__(256) void k_G2(const float* __restrict__ inv2T,
                                            const float* __restrict__ c2p,
                                            float* __restrict__ g2) {
  const int gid = blockIdx.x * 256 + threadIdx.x;  // 16384
  const int i = gid >> 7;   // wave-uniform
  const int o = gid & 127;  // lane
  float s = 0.f;
  for (int m = 0; m < 128; ++m) s += inv2T[m * 128 + i] * c2p[m * 128 + o];
  g2[i * 128 + o] = s;
}

// ---------- g1 = z1 - W * g2 ----------
__global__ __launch_bounds__(256) void k_G1(const float* __restrict__ W,
                                            const float* __restrict__ z1,
                                            const float* __restrict__ g2,
                                            float* __restrict__ g1) {
  const int gid = blockIdx.x * 256 + threadIdx.x;  // 16384
  const int i = gid >> 7;   // wave-uniform
  const int o = gid & 127;  // lane
  float s = z1[i * 128 + o];
  for (int m = 0; m < 128; ++m) s -= W[i * 128 + m] * g2[m * 128 + o];
  g1[i * 128 + o] = s;
}

// ---------- R = [P | Q] (128 x 384) and y0 ----------
__global__ __launch_bounds__(256) void k_R(const float* __restrict__ B1,
                                           const float* __restrict__ B2,
                                           const float* __restrict__ D21,
                                           const float* __restrict__ D22,
                                           const float* __restrict__ g1,
                                           const float* __restrict__ g2,
                                           const float* __restrict__ xF,
                                           float* __restrict__ R,
                                           float* __restrict__ y0) {
  const int gid = blockIdx.x * 256 + threadIdx.x;  // need 49280
  if (gid < 32768) {
    const int o = gid >> 8;   // wave-uniform
    const int l = gid & 255;  // lane
    float s = D21[o * 256 + l];
    for (int m = 0; m < 128; ++m) {
      s += g1[m * 128 + o] * B1[m * 256 + l];
      s += g2[m * 128 + o] * B1[(128 + m) * 256 + l];
    }
    R[o * 384 + l] = s;
  } else if (gid < 49152) {
    const int t = gid - 32768;
    const int o = t >> 7;    // wave-uniform
    const int i = t & 127;   // lane
    float s = D22[o * 128 + i];
    for (int m = 0; m < 128; ++m) {
      s += g1[m * 128 + o] * B2[m * 128 + i];
      s += g2[m * 128 + o] * B2[(128 + m) * 128 + i];
    }
    R[o * 384 + 256 + i] = s;
  } else if (gid < 49280) {
    const int o = gid - 49152;
    float s = 0.f;
    for (int m = 0; m < 128; ++m) {
      s += g1[m * 128 + o] * xF[m];
      s += g2[m * 128 + o] * xF[128 + m];
    }
    y0[o] = s;
  }
}

// ---------- transpose u (8192x128) into vw rows 256..383 (u^T, coalesced) ----------
__global__ __launch_bounds__(256) void k_T(const float* __restrict__ u,
                                           float* __restrict__ vw) {
  __shared__ float buf[128 * 65];
  const int t = threadIdx.x;
  const int b0 = blockIdx.x * 64;
#pragma unroll
  for (int q = 0; q < 32; ++q) {
    const int idx = q * 256 + t;
    const int bl = idx >> 7;
    const int i = idx & 127;
    buf[i * 65 + bl] = u[(b0 + bl) * 128 + i];
  }
  __syncthreads();
#pragma unroll
  for (int q = 0; q < 32; ++q) {
    const int idx = q * 256 + t;
    const int i = idx >> 6;
    const int bl = idx & 63;
    vw[(256 + i) * NB + b0 + bl] = buf[i * 65 + bl];
  }
}

// ---------- vw[l][b] = cx[l] + D12[l,:]·u[b,:] via u^T (GEMM-style) ----------
__global__ __launch_bounds__(256) void k_du(const float* __restrict__ D12,
                                            const float* __restrict__ cx,
                                            float* __restrict__ vw) {
  __shared__ float Dl[8 * 128];
  const int t = threadIdx.x;
  const int l0 = blockIdx.y * 8;
#pragma unroll
  for (int q = 0; q < 4; ++q) Dl[q * 256 + t] = D12[l0 * 128 + q * 256 + t];
  __syncthreads();
  const float4* vw4 = (const float4*)vw;
  float4* vw4o = (float4*)vw;
  const int b4 = blockIdx.x * 256 + t;
  float4 acc[8];
#pragma unroll
  for (int j = 0; j < 8; ++j) {
    const float cj = cx[l0 + j];
    acc[j] = make_float4(cj, cj, cj, cj);
  }
#pragma unroll 4
  for (int i = 0; i < 128; ++i) {
    const float4 wv = vw4[(256 + i) * 2048 + b4];
#pragma unroll
    for (int j = 0; j < 8; ++j) {
      const float d = Dl[j * 128 + i];  // broadcast
      acc[j].x += d * wv.x;
      acc[j].y += d * wv.y;
      acc[j].z += d * wv.z;
      acc[j].w += d * wv.w;
    }
  }
#pragma unroll
  for (int j = 0; j < 8; ++j) vw4o[(l0 + j) * 2048 + b4] = acc[j];
}

// ---------- right-looking 64-step scan chunk: v[64] in REGISTERS ----------
// step li: w = tanh(v[li]*rLam); then v[l2] += D[l2][li]*w (packed-column broadcast
// float4 loads). Fully unrolled -> all v[] indices compile-time. No LDS at all.
__global__ __launch_bounds__(64) void k_scan(const float* __restrict__ cpack,
                                             const float* __restrict__ rLam,
                                             float* __restrict__ vw, int c) {
  const int t = threadIdx.x;
  const int b = blockIdx.x * 64 + t;
  const int l0 = c * 64;
  const float4* cp4 = (const float4*)(cpack + c * CPACK_STRIDE);
  float v[64];
#pragma unroll
  for (int li = 0; li < 64; ++li) v[li] = vw[(l0 + li) * NB + b];
  sfor<64>([&](auto LI) {
    constexpr int li = decltype(LI)::value;
    const float w = fast_tanh(v[li] * rLam[l0 + li]);
    vw[(l0 + li) * NB + b] = w;  // fire-and-forget
    constexpr int n = 63 - li;
    constexpr int off4 = coff(li) / 4;
    sfor<(n + 3) / 4>([&](auto Q) {
      constexpr int q = decltype(Q)::value;
      const float4 d = cp4[off4 + q];
      if constexpr (4 * q + 0 < n) v[li + 1 + 4 * q + 0] += d.x * w;
      if constexpr (4 * q + 1 < n) v[li + 1 + 4 * q + 1] += d.y * w;
      if constexpr (4 * q + 2 < n) v[li + 1 + 4 * q + 2] += d.z * w;
      if constexpr (4 * q + 3 < n) v[li + 1 + 4 * q + 3] += d.w * w;
    });
  });
}

// ---------- cross-chunk rank-64 update: vw[l'][b] += D11[l', chunk]·w[chunk][b] ----------
__global__ __launch_bounds__(256) void k_upd(const float* __restrict__ D11,
                                             float* __restrict__ vw, int c) {
  float4* vw4 = (float4*)vw;
  const int b4 = blockIdx.x * 256 + threadIdx.x;
  const int lp0 = (c + 1) * 64 + blockIdx.y * 8;
  const int k0 = c * 64;
  float4 acc[8];
#pragma unroll
  for (int j = 0; j < 8; ++j) acc[j] = vw4[(lp0 + j) * 2048 + b4];
  for (int k = 0; k < 64; ++k) {
    const float4 wv = vw4[(k0 + k) * 2048 + b4];
#pragma unroll
    for (int j = 0; j < 8; ++j) {
      const float d = D11[(lp0 + j) * 256 + k0 + k];  // wave-uniform scalar
      acc[j].x += d * wv.x;
      acc[j].y += d * wv.y;
      acc[j].z += d * wv.z;
      acc[j].w += d * wv.w;
    }
  }
#pragma unroll
  for (int j = 0; j < 8; ++j) vw4[(lp0 + j) * 2048 + b4] = acc[j];
}

// ---------- y[b][o] = y0[o] + sum_{k<384} R[o][k] vw[k][b] ----------
__global__ __launch_bounds__(256) void k_y(const float* __restrict__ vw,
                                           const float* __restrict__ R,
                                           const float* __restrict__ y0,
                                           float* __restrict__ y) {
  __shared__ float Rl[1536];
  const int tid = threadIdx.x;
  const int bid = blockIdx.x;  // 256 blocks
  const int gx = bid & 7;      // b-tile (XCD-aligned)
  const int gy = bid >> 3;     // o-tile, 0..31
  const int o0 = gy * 4;
#pragma unroll
  for (int q = 0; q < 6; ++q) Rl[q * 256 + tid] = R[o0 * 384 + q * 256 + tid];
  __syncthreads();

  const float4* vw4 = (const float4*)vw;
  const int b4 = gx * 256 + tid;
  float acc[4][4];
#pragma unroll
  for (int j = 0; j < 4; ++j) {
    const float y0j = y0[o0 + j];
#pragma unroll
    for (int bi = 0; bi < 4; ++bi) acc[bi][j] = y0j;
  }
#pragma unroll 4
  for (int k = 0; k < 384; k += 4) {
    const float4 w0 = vw4[(k + 0) * 2048 + b4];
    const float4 w1 = vw4[(k + 1) * 2048 + b4];
    const float4 w2 = vw4[(k + 2) * 2048 + b4];
    const float4 w3 = vw4[(k + 3) * 2048 + b4];
#pragma unroll
    for (int j = 0; j < 4; ++j) {
      const float4 r = *(const float4*)&Rl[j * 384 + k];
      acc[0][j] += r.x * w0.x + r.y * w1.x + r.z * w2.x + r.w * w3.x;
      acc[1][j] += r.x * w0.y + r.y * w1.y + r.z * w2.y + r.w * w3.y;
      acc[2][j] += r.x * w0.z + r.y * w1.z + r.z * w2.z + r.w * w3.z;
      acc[3][j] += r.x * w0.w + r.y * w1.w + r.z * w2.w + r.w * w3.w;
    }
  }
  const int b0 = b4 * 4;
#pragma unroll
  for (int bi = 0; bi < 4; ++bi) {
    *(float4*)&y[(b0 + bi) * 128 + o0] =
        make_float4(acc[bi][0], acc[bi][1], acc[bi][2], acc[bi][3]);
  }
}

extern "C" void kernel_launch(void* const* d_in, const int* in_sizes, int n_in,
                              void* d_out, int out_size, void* d_ws, size_t ws_size,
                              hipStream_t stream) {
  const float* u   = (const float*)d_in[0];   // (8192,1,128)
  const float* x   = (const float*)d_in[1];   // (1,1,256)
  const float* Fm  = (const float*)d_in[2];   // (256,256)
  const float* B1  = (const float*)d_in[3];   // (256,256)
  const float* B2  = (const float*)d_in[4];   // (256,128)
  const float* C1  = (const float*)d_in[5];   // (256,256)
  const float* C2  = (const float*)d_in[6];   // (128,256)
  const float* D11 = (const float*)d_in[7];   // (256,256) strictly lower
  const float* D12 = (const float*)d_in[8];   // (256,128)
  const float* D21 = (const float*)d_in[9];   // (128,256)
  const float* D22 = (const float*)d_in[10];  // (128,128)
  const float* E   = (const float*)d_in[11];  // (256,256)
  const float* Lam = (const float*)d_in[12];  // (256,)
  float* y = (float*)d_out;                   // (8192,1,128) fp32

  float* F = (float*)d_ws;                     // ~13.4 MB used
  float* vw    = F;                            // 384*8192 (rows 256..383 = u^T)
  float* SMb   = F + 384 * NB;
  float* inv1T = SMb;                          // 16384
  float* Wm    = SMb + 16384;
  float* z1    = SMb + 32768;
  float* STt   = SMb + 49152;
  float* c2p   = SMb + 65536;
  float* inv2T = SMb + 81920;
  float* g2    = SMb + 98304;
  float* g1    = SMb + 114688;
  float* Rm    = SMb + 131072;                 // 128*384
  float* y0v   = SMb + 180224;                 // 128
  float* cx    = SMb + 180352;                 // 256
  float* xF    = SMb + 180608;                 // 256
  float* rLam  = SMb + 180864;                 // 256
  float* cpack = SMb + 181120;                 // 4*2176

  // small precompute + Schur solve chain for G = C2 * inv(E)  (E^T G^T = C2^T)
  k_prep<<<1, 256, 0, stream>>>(x, C1, Fm, Lam, cx, xF, rLam);
  k_pack<<<4, 64, 0, stream>>>(D11, cpack);
  k_inv<<<1, 1024, 0, stream>>>(E, 256, inv1T);          // inv(A11), A = E^T
  k_WZ<<<128, 256, 0, stream>>>(E, C2, inv1T, Wm, z1);
  k_SC<<<128, 256, 0, stream>>>(E, C2, Wm, z1, STt, c2p);
  k_inv<<<1, 1024, 0, stream>>>(STt, 128, inv2T);        // inv(S)
  k_G2<<<64, 256, 0, stream>>>(inv2T, c2p, g2);
  k_G1<<<64, 256, 0, stream>>>(Wm, z1, g2, g1);
  k_R<<<193, 256, 0, stream>>>(B1, B2, D21, D22, g1, g2, xF, Rm, y0v);

  // batch pipeline: u transpose, v-init, chunked scan, output GEMM
  k_T<<<128, 256, 0, stream>>>(u, vw);
  k_du<<<dim3(8, 32), 256, 0, stream>>>(D12, cx, vw);
  for (int c = 0; c < 4; ++c) {
    k_scan<<<128, 64, 0, stream>>>(cpack, rLam, vw, c);
    if (c < 3) {
      const int tiles = (256 - (c + 1) * 64) / 8;
      k_upd<<<dim3(8, tiles), 256, 0, stream>>>(D11, vw, c);
    }
  }
  k_y<<<256, 256, 0, stream>>>(vw, Rm, y0v, y);
}

// Round 6
// 404.855 us; speedup vs baseline: 1.5495x; 1.2302x over previous
//
#include <hip/hip_runtime.h>
#include <utility>

// Problem constants
// DIM_IN=128, DIM_OUT=128, DIM_X=256, L=256, BATCH=8192, fp32 everywhere.
#define NB 8192

// ---------- static_for helper (compile-time register indices) ----------
template <typename F, size_t... I>
__device__ __forceinline__ void sfor_impl(F&& f, std::index_sequence<I...>) {
  (f(std::integral_constant<int, (int)I>{}), ...);
}
template <int N, typename F>
__device__ __forceinline__ void sfor(F&& f) {
  sfor_impl((F&&)f, std::make_index_sequence<N>{});
}

// packed-column-triangle offset: column li holds D[l2][li], l2=li+1..63, padded to x4
constexpr int coff(int li) {
  int o = 0;
  for (int j = 0; j < li; ++j) o += ((63 - j) + 3) & ~3;
  return o;
}
#define CPACK_STRIDE 2176  // > coff(63), float4-aligned

// fast tanh: 1 - 2/(exp(2x)+1). Correct limits at +/-inf.
__device__ __forceinline__ float fast_tanh(float x) {
  const float e = __expf(2.0f * x);
  return 1.0f - 2.0f / (e + 1.0f);
}

// =================== device functions (fused into mega kernels) ===================

// ---------- prep: cx[l] = C1[l,:]·x ; xF[k] = Fm[k,:]·x ; rLam = 1/Lam ----------
__device__ void dev_prep(const float* __restrict__ x, const float* __restrict__ C1,
                         const float* __restrict__ Fm, const float* __restrict__ Lam,
                         float* __restrict__ cx, float* __restrict__ xF,
                         float* __restrict__ rLam, int t) {
  float s1 = 0.f, s2 = 0.f;
  for (int i = 0; i < 256; ++i) {
    const float xi = x[i];
    s1 += C1[t * 256 + i] * xi;
    s2 += Fm[t * 256 + i] * xi;
  }
  cx[t] = s1;
  xF[t] = s2;
  rLam[t] = 1.0f / Lam[t];
}

// ---------- pack D11 chunk-triangles column-major (one 256-thread block) ----------
__device__ void dev_pack(const float* __restrict__ D11, float* __restrict__ cpack,
                         int t) {
  const int c = t >> 6;
  const int lane = t & 63;
  int off = 0;
  for (int li = 0; li < 63; ++li) {
    if (lane < 63 - li)
      cpack[c * CPACK_STRIDE + off + lane] =
          D11[(c * 64 + li + 1 + lane) * 256 + (c * 64 + li)];
    off += ((63 - li) + 3) & ~3;
  }
}

// ---------- blocked-panel GJ inverse of 128x128, 256 threads, 8x8 register tiles ---
// A[r][c] = srcT[c*ld + r]; output dstT[c*128 + r] = Ainv[r][c].
// Per outer step s (16-col panel): stage panel cols + old panel rows; 16 lanes invert
// the 16x16 pivot block (shfl); 256 threads build M = [-A_np*invD ; invD]; rank-16
// register-tiled update (each lane reads DIFFERENT LDS data -> 4x fewer LDS instr
// than the 1024-thread broadcast scheme that measured 63us).
__device__ void dev_inv(const float* __restrict__ srcT, int ld,
                        float* __restrict__ dstT, int tid) {
  __shared__ float Pcols[128][20];  // [r][kk] current panel columns (pad 20)
  __shared__ float MB[128][20];     // [r][kk] panel transform M (pad 20)
  __shared__ float Ar[16][132];     // [kk][c] OLD panel-row values (pad 132)
  __shared__ float invD[16 * 20];   // [kk][j] pivot-block inverse (pad 20)
  const int ti = tid >> 4, tj = tid & 15;
  const int R = ti * 8, C = tj * 8;
  float a[8][8];
#pragma unroll
  for (int i = 0; i < 8; ++i)
#pragma unroll
    for (int j = 0; j < 8; ++j) a[i][j] = srcT[(C + j) * ld + (R + i)];

  for (int s = 0; s < 8; ++s) {
    // ---- stage panel columns (col-tile owners) + old panel rows (row-tile owners)
    if ((tj >> 1) == s) {
      const int c0 = C - 16 * s;
#pragma unroll
      for (int i = 0; i < 8; ++i)
#pragma unroll
        for (int j = 0; j < 8; ++j) Pcols[R + i][c0 + j] = a[i][j];
    }
    if ((ti >> 1) == s) {
      const int r0 = R - 16 * s;
#pragma unroll
      for (int i = 0; i < 8; ++i)
#pragma unroll
        for (int j = 0; j < 8; ++j) Ar[r0 + i][C + j] = a[i][j];
    }
    __syncthreads();

    // ---- 1a: invert 16x16 pivot block, 16 lanes, registers (verified GJ math) ----
    if (tid < 16) {
      float q[16];
#pragma unroll
      for (int g = 0; g < 4; ++g) {
        const float4 v = *(const float4*)&Pcols[s * 16 + tid][4 * g];
        q[4 * g] = v.x; q[4 * g + 1] = v.y; q[4 * g + 2] = v.z; q[4 * g + 3] = v.w;
      }
#pragma unroll
      for (int kk = 0; kk < 16; ++kk) {
        float ps[16];
#pragma unroll
        for (int j = 0; j < 16; ++j) ps[j] = __shfl(q[j], kk, 16);
        const float piv = 1.0f / ps[kk];
#pragma unroll
        for (int j = 0; j < 16; ++j) ps[j] = (j == kk) ? piv : ps[j] * piv;
        const bool isP = (tid == kk);
        const float te = isP ? -1.0f : q[kk];
#pragma unroll
        for (int j = 0; j < 16; ++j) {
          const float base = (isP || j == kk) ? 0.0f : q[j];
          q[j] = base - te * ps[j];
        }
      }
#pragma unroll
      for (int j = 0; j < 16; ++j) invD[tid * 20 + j] = q[j];  // row tid of invD
    }
    __syncthreads();

    // ---- 1b: M[r][0..15], thread (r = tid&127, h = tid>>7) does cols 8h..8h+7 ----
    {
      const int r = tid & 127, h = tid >> 7;
      float mv[8];
      if ((r >> 4) == s) {
        const float4 m0 = *(const float4*)&invD[(r & 15) * 20 + 8 * h];
        const float4 m1 = *(const float4*)&invD[(r & 15) * 20 + 8 * h + 4];
        mv[0] = m0.x; mv[1] = m0.y; mv[2] = m0.z; mv[3] = m0.w;
        mv[4] = m1.x; mv[5] = m1.y; mv[6] = m1.z; mv[7] = m1.w;
      } else {
#pragma unroll
        for (int j = 0; j < 8; ++j) mv[j] = 0.f;
#pragma unroll
        for (int g = 0; g < 4; ++g) {
          const float4 p = *(const float4*)&Pcols[r][4 * g];
          const float pc[4] = {p.x, p.y, p.z, p.w};
#pragma unroll
          for (int q = 0; q < 4; ++q) {
            const int kk = 4 * g + q;
            const float4 d0 = *(const float4*)&invD[kk * 20 + 8 * h];
            const float4 d1 = *(const float4*)&invD[kk * 20 + 8 * h + 4];
            mv[0] -= pc[q] * d0.x; mv[1] -= pc[q] * d0.y;
            mv[2] -= pc[q] * d0.z; mv[3] -= pc[q] * d0.w;
            mv[4] -= pc[q] * d1.x; mv[5] -= pc[q] * d1.y;
            mv[6] -= pc[q] * d1.z; mv[7] -= pc[q] * d1.w;
          }
        }
      }
      *(float4*)&MB[r][8 * h] = make_float4(mv[0], mv[1], mv[2], mv[3]);
      *(float4*)&MB[r][8 * h + 4] = make_float4(mv[4], mv[5], mv[6], mv[7]);
    }
    __syncthreads();

    // ---- phase 2: register-tiled rank-16 update ----
    if ((tj >> 1) == s) {
      // panel columns replaced by M
      const int c0 = C - 16 * s;
#pragma unroll
      for (int i = 0; i < 8; ++i)
#pragma unroll
        for (int j = 0; j < 8; ++j) a[i][j] = MB[R + i][c0 + j];
    } else {
      if ((ti >> 1) == s) {
#pragma unroll
        for (int i = 0; i < 8; ++i)
#pragma unroll
          for (int j = 0; j < 8; ++j) a[i][j] = 0.f;
      }
#pragma unroll
      for (int half = 0; half < 2; ++half) {
        float arr[8][8];
#pragma unroll
        for (int kk = 0; kk < 8; ++kk) {
          const float4 p0 = *(const float4*)&Ar[half * 8 + kk][C];
          const float4 p1 = *(const float4*)&Ar[half * 8 + kk][C + 4];
          arr[kk][0] = p0.x; arr[kk][1] = p0.y; arr[kk][2] = p0.z; arr[kk][3] = p0.w;
          arr[kk][4] = p1.x; arr[kk][5] = p1.y; arr[kk][6] = p1.z; arr[kk][7] = p1.w;
        }
#pragma unroll
        for (int i = 0; i < 8; ++i) {
          const float4 m0 = *(const float4*)&MB[R + i][half * 8];
          const float4 m1 = *(const float4*)&MB[R + i][half * 8 + 4];
          const float mi[8] = {m0.x, m0.y, m0.z, m0.w, m1.x, m1.y, m1.z, m1.w};
#pragma unroll
          for (int kk = 0; kk < 8; ++kk)
#pragma unroll
            for (int j = 0; j < 8; ++j) a[i][j] += mi[kk] * arr[kk][j];
        }
      }
    }
    __syncthreads();
  }
#pragma unroll
  for (int i = 0; i < 8; ++i)
#pragma unroll
    for (int j = 0; j < 8; ++j) dstT[(C + j) * 128 + (R + i)] = a[i][j];
}

// ---------- transpose u (8192x128) into vw rows 256..383 (two 64-row halves) ------
__device__ void dev_T(const float* __restrict__ u, float* __restrict__ vw, int bid,
                      int t) {
  __shared__ float buf[64 * 65];
  const int b0 = bid * 64;
#pragma unroll
  for (int h = 0; h < 2; ++h) {
#pragma unroll
    for (int q = 0; q < 16; ++q) {
      const int idx = q * 256 + t;
      const int bl = idx >> 6;
      const int i2 = idx & 63;
      buf[i2 * 65 + bl] = u[(b0 + bl) * 128 + 64 * h + i2];
    }
    __syncthreads();
#pragma unroll
    for (int q = 0; q < 16; ++q) {
      const int idx = q * 256 + t;
      const int i2 = idx >> 6;
      const int bl = idx & 63;
      vw[(256 + 64 * h + i2) * NB + b0 + bl] = buf[i2 * 65 + bl];
    }
    __syncthreads();
  }
}

// ---------- vw[l][b] = cx[l] + D12[l,:]·u[b,:] via u^T (GEMM-style) ----------
__device__ void dev_du(const float* __restrict__ D12, const float* __restrict__ cx,
                       float* __restrict__ vw, int bid, int t) {
  __shared__ float Dl[8 * 128];
  const int bx = bid & 7;
  const int l0 = (bid >> 3) * 8;
#pragma unroll
  for (int q = 0; q < 4; ++q) Dl[q * 256 + t] = D12[l0 * 128 + q * 256 + t];
  __syncthreads();
  const float4* vw4 = (const float4*)vw;
  float4* vw4o = (float4*)vw;
  const int b4 = bx * 256 + t;
  float4 acc[8];
#pragma unroll
  for (int j = 0; j < 8; ++j) {
    const float cj = cx[l0 + j];
    acc[j] = make_float4(cj, cj, cj, cj);
  }
#pragma unroll 4
  for (int i = 0; i < 128; ++i) {
    const float4 wv = vw4[(256 + i) * 2048 + b4];
#pragma unroll
    for (int j = 0; j < 8; ++j) {
      const float d = Dl[j * 128 + i];
      acc[j].x += d * wv.x;
      acc[j].y += d * wv.y;
      acc[j].z += d * wv.z;
      acc[j].w += d * wv.w;
    }
  }
#pragma unroll
  for (int j = 0; j < 8; ++j) vw4o[(l0 + j) * 2048 + b4] = acc[j];
}

// ---------- W = invA11 * A12 ; z1 = invA11 * c1 ----------
__device__ void dev_WZ(const float* __restrict__ E, const float* __restrict__ C2,
                       const float* __restrict__ inv1T, float* __restrict__ W,
                       float* __restrict__ z1, int gid) {
  const int half = gid >> 14;
  const int idx = gid & 16383;
  const int j = idx >> 7;   // wave-uniform
  const int i = idx & 127;  // lane
  float s = 0.f;
  if (half == 0) {
    for (int m = 0; m < 128; ++m) s += inv1T[m * 128 + i] * E[(128 + j) * 256 + m];
    W[i * 128 + j] = s;
  } else {
    for (int m = 0; m < 128; ++m) s += inv1T[m * 128 + i] * C2[j * 256 + m];
    z1[i * 128 + j] = s;
  }
}

// ---------- S^T = (A22 - A21 W)^T ; c2p = c2 - A21 z1 ----------
__device__ void dev_SC(const float* __restrict__ E, const float* __restrict__ C2,
                       const float* __restrict__ W, const float* __restrict__ z1,
                       float* __restrict__ STt, float* __restrict__ c2p, int gid) {
  if (gid < 16384) {
    const int jj = gid >> 7;
    const int i = gid & 127;
    float s = E[(128 + jj) * 256 + 128 + i];
    for (int m = 0; m < 128; ++m) s -= E[m * 256 + 128 + i] * W[m * 128 + jj];
    STt[jj * 128 + i] = s;
  } else {
    const int idx = gid - 16384;
    const int i = idx >> 7;
    const int o = idx & 127;
    float s = C2[o * 256 + 128 + i];
    for (int m = 0; m < 128; ++m) s -= E[m * 256 + 128 + i] * z1[m * 128 + o];
    c2p[i * 128 + o] = s;
  }
}

// ---------- g2 = invS * c2p ----------
__device__ void dev_G2(const float* __restrict__ inv2T, const float* __restrict__ c2p,
                       float* __restrict__ g2, int gid) {
  const int i = gid >> 7;
  const int o = gid & 127;
  float s = 0.f;
  for (int m = 0; m < 128; ++m) s += inv2T[m * 128 + i] * c2p[m * 128 + o];
  g2[i * 128 + o] = s;
}

// ---------- g1 = z1 - W * g2 ----------
__device__ void dev_G1(const float* __restrict__ W, const float* __restrict__ z1,
                       const float* __restrict__ g2, float* __restrict__ g1, int gid) {
  const int i = gid >> 7;
  const int o = gid & 127;
  float s = z1[i * 128 + o];
  for (int m = 0; m < 128; ++m) s -= W[i * 128 + m] * g2[m * 128 + o];
  g1[i * 128 + o] = s;
}

// ---------- R = [P | Q] (128 x 384) and y0 ----------
__device__ void dev_R(const float* __restrict__ B1, const float* __restrict__ B2,
                      const float* __restrict__ D21, const float* __restrict__ D22,
                      const float* __restrict__ g1, const float* __restrict__ g2,
                      const float* __restrict__ xF, float* __restrict__ R,
                      float* __restrict__ y0, int gid) {
  if (gid < 32768) {
    const int o = gid >> 8;
    const int l = gid & 255;
    float s = D21[o * 256 + l];
    for (int m = 0; m < 128; ++m) {
      s += g1[m * 128 + o] * B1[m * 256 + l];
      s += g2[m * 128 + o] * B1[(128 + m) * 256 + l];
    }
    R[o * 384 + l] = s;
  } else if (gid < 49152) {
    const int t2 = gid - 32768;
    const int o = t2 >> 7;
    const int i = t2 & 127;
    float s = D22[o * 128 + i];
    for (int m = 0; m < 128; ++m) {
      s += g1[m * 128 + o] * B2[m * 128 + i];
      s += g2[m * 128 + o] * B2[(128 + m) * 128 + i];
    }
    R[o * 384 + 256 + i] = s;
  } else if (gid < 49280) {
    const int o = gid - 49152;
    float s = 0.f;
    for (int m = 0; m < 128; ++m) {
      s += g1[m * 128 + o] * xF[m];
      s += g2[m * 128 + o] * xF[128 + m];
    }
    y0[o] = s;
  }
}

// ---------- right-looking 64-step scan chunk: v[64] in REGISTERS ----------
__device__ void dev_scan(const float* __restrict__ cpack,
                         const float* __restrict__ rLam, float* __restrict__ vw,
                         int c, int bid, int t) {
  const int b = bid * 256 + t;
  const int l0 = c * 64;
  const float4* cp4 = (const float4*)(cpack + c * CPACK_STRIDE);
  float v[64];
#pragma unroll
  for (int li = 0; li < 64; ++li) v[li] = vw[(l0 + li) * NB + b];
  sfor<64>([&](auto LI) {
    constexpr int li = decltype(LI)::value;
    const float w = fast_tanh(v[li] * rLam[l0 + li]);
    vw[(l0 + li) * NB + b] = w;  // fire-and-forget
    constexpr int n = 63 - li;
    constexpr int off4 = coff(li) / 4;
    sfor<(n + 3) / 4>([&](auto Q) {
      constexpr int q = decltype(Q)::value;
      const float4 d = cp4[off4 + q];
      if constexpr (4 * q + 0 < n) v[li + 1 + 4 * q + 0] += d.x * w;
      if constexpr (4 * q + 1 < n) v[li + 1 + 4 * q + 1] += d.y * w;
      if constexpr (4 * q + 2 < n) v[li + 1 + 4 * q + 2] += d.z * w;
      if constexpr (4 * q + 3 < n) v[li + 1 + 4 * q + 3] += d.w * w;
    });
  });
}

// ---------- cross-chunk rank-64 update ----------
__device__ void dev_upd(const float* __restrict__ D11, float* __restrict__ vw, int c,
                        int bid, int t) {
  float4* vw4 = (float4*)vw;
  const int b4 = (bid & 7) * 256 + t;
  const int lp0 = (c + 1) * 64 + (bid >> 3) * 8;
  const int k0 = c * 64;
  float4 acc[8];
#pragma unroll
  for (int j = 0; j < 8; ++j) acc[j] = vw4[(lp0 + j) * 2048 + b4];
  for (int k = 0; k < 64; ++k) {
    const float4 wv = vw4[(k0 + k) * 2048 + b4];
#pragma unroll
    for (int j = 0; j < 8; ++j) {
      const float d = D11[(lp0 + j) * 256 + k0 + k];  // wave-uniform scalar
      acc[j].x += d * wv.x;
      acc[j].y += d * wv.y;
      acc[j].z += d * wv.z;
      acc[j].w += d * wv.w;
    }
  }
#pragma unroll
  for (int j = 0; j < 8; ++j) vw4[(lp0 + j) * 2048 + b4] = acc[j];
}

// =================== mega kernels (block-range dispatch) ===================

__global__ __launch_bounds__(256) void mega1(const float* u, const float* x,
                                             const float* C1, const float* Fm,
                                             const float* Lam, const float* D11,
                                             const float* E, float* vw, float* cx,
                                             float* xF, float* rLam, float* cpack,
                                             float* inv1T) {
  const int bid = blockIdx.x;
  const int t = threadIdx.x;
  if (bid < 128) dev_T(u, vw, bid, t);
  else if (bid == 128) dev_prep(x, C1, Fm, Lam, cx, xF, rLam, t);
  else if (bid == 129) dev_pack(D11, cpack, t);
  else dev_inv(E, 256, inv1T, t);  // bid == 130
}

__global__ __launch_bounds__(256) void mega2(const float* D12, const float* cx,
                                             float* vw, const float* E,
                                             const float* C2, const float* inv1T,
                                             float* W, float* z1) {
  const int bid = blockIdx.x;
  const int t = threadIdx.x;
  if (bid < 256) dev_du(D12, cx, vw, bid, t);
  else dev_WZ(E, C2, inv1T, W, z1, (bid - 256) * 256 + t);
}

__global__ __launch_bounds__(256) void mega3(const float* cpack, const float* rLam,
                                             float* vw, const float* E,
                                             const float* C2, const float* W,
                                             const float* z1, float* STt,
                                             float* c2p) {
  const int bid = blockIdx.x;
  const int t = threadIdx.x;
  if (bid < 32) dev_scan(cpack, rLam, vw, 0, bid, t);
  else dev_SC(E, C2, W, z1, STt, c2p, (bid - 32) * 256 + t);
}

__global__ __launch_bounds__(256) void mega4(const float* D11, float* vw,
                                             const float* STt, float* inv2T) {
  const int bid = blockIdx.x;
  const int t = threadIdx.x;
  if (bid < 192) dev_upd(D11, vw, 0, bid, t);
  else dev_inv(STt, 128, inv2T, t);
}

__global__ __launch_bounds__(256) void mega5(const float* cpack, const float* rLam,
                                             float* vw, const float* inv2T,
                                             const float* c2p, float* g2) {
  const int bid = blockIdx.x;
  const int t = threadIdx.x;
  if (bid < 32) dev_scan(cpack, rLam, vw, 1, bid, t);
  else dev_G2(inv2T, c2p, g2, (bid - 32) * 256 + t);
}

__global__ __launch_bounds__(256) void mega6(const float* D11, float* vw,
                                             const float* W, const float* z1,
                                             const float* g2, float* g1) {
  const int bid = blockIdx.x;
  const int t = threadIdx.x;
  if (bid < 128) dev_upd(D11, vw, 1, bid, t);
  else dev_G1(W, z1, g2, g1, (bid - 128) * 256 + t);
}

__global__ __launch_bounds__(256) void mega7(const float* cpack, const float* rLam,
                                             float* vw, const float* B1,
                                             const float* B2, const float* D21,
                                             const float* D22, const float* g1,
                                             const float* g2, const float* xF,
                                             float* R, float* y0) {
  const int bid = blockIdx.x;
  const int t = threadIdx.x;
  if (bid < 32) dev_scan(cpack, rLam, vw, 2, bid, t);
  else dev_R(B1, B2, D21, D22, g1, g2, xF, R, y0, (bid - 32) * 256 + t);
}

__global__ __launch_bounds__(256) void mega8(const float* D11, float* vw) {
  dev_upd(D11, vw, 2, blockIdx.x, threadIdx.x);
}

__global__ __launch_bounds__(256) void mega9(const float* cpack, const float* rLam,
                                             float* vw) {
  dev_scan(cpack, rLam, vw, 3, blockIdx.x, threadIdx.x);
}

// ---------- y[b][o] = y0[o] + sum_{k<384} R[o][k] vw[k][b] ----------
__global__ __launch_bounds__(256) void k_y(const float* __restrict__ vw,
                                           const float* __restrict__ R,
                                           const float* __restrict__ y0,
                                           float* __restrict__ y) {
  __shared__ float Rl[1536];
  const int tid = threadIdx.x;
  const int bid = blockIdx.x;  // 256 blocks
  const int gx = bid & 7;      // b-tile (XCD-aligned)
  const int gy = bid >> 3;     // o-tile, 0..31
  const int o0 = gy * 4;
#pragma unroll
  for (int q = 0; q < 6; ++q) Rl[q * 256 + tid] = R[o0 * 384 + q * 256 + tid];
  __syncthreads();

  const float4* vw4 = (const float4*)vw;
  const int b4 = gx * 256 + tid;
  float acc[4][4];
#pragma unroll
  for (int j = 0; j < 4; ++j) {
    const float y0j = y0[o0 + j];
#pragma unroll
    for (int bi = 0; bi < 4; ++bi) acc[bi][j] = y0j;
  }
#pragma unroll 4
  for (int k = 0; k < 384; k += 4) {
    const float4 w0 = vw4[(k + 0) * 2048 + b4];
    const float4 w1 = vw4[(k + 1) * 2048 + b4];
    const float4 w2 = vw4[(k + 2) * 2048 + b4];
    const float4 w3 = vw4[(k + 3) * 2048 + b4];
#pragma unroll
    for (int j = 0; j < 4; ++j) {
      const float4 r = *(const float4*)&Rl[j * 384 + k];
      acc[0][j] += r.x * w0.x + r.y * w1.x + r.z * w2.x + r.w * w3.x;
      acc[1][j] += r.x * w0.y + r.y * w1.y + r.z * w2.y + r.w * w3.y;
      acc[2][j] += r.x * w0.z + r.y * w1.z + r.z * w2.z + r.w * w3.z;
      acc[3][j] += r.x * w0.w + r.y * w1.w + r.z * w2.w + r.w * w3.w;
    }
  }
  const int b0 = b4 * 4;
#pragma unroll
  for (int bi = 0; bi < 4; ++bi) {
    *(float4*)&y[(b0 + bi) * 128 + o0] =
        make_float4(acc[bi][0], acc[bi][1], acc[bi][2], acc[bi][3]);
  }
}

extern "C" void kernel_launch(void* const* d_in, const int* in_sizes, int n_in,
                              void* d_out, int out_size, void* d_ws, size_t ws_size,
                              hipStream_t stream) {
  const float* u   = (const float*)d_in[0];   // (8192,1,128)
  const float* x   = (const float*)d_in[1];   // (1,1,256)
  const float* Fm  = (const float*)d_in[2];   // (256,256)
  const float* B1  = (const float*)d_in[3];   // (256,256)
  const float* B2  = (const float*)d_in[4];   // (256,128)
  const float* C1  = (const float*)d_in[5];   // (256,256)
  const float* C2  = (const float*)d_in[6];   // (128,256)
  const float* D11 = (const float*)d_in[7];   // (256,256) strictly lower
  const float* D12 = (const float*)d_in[8];   // (256,128)
  const float* D21 = (const float*)d_in[9];   // (128,256)
  const float* D22 = (const float*)d_in[10];  // (128,128)
  const float* E   = (const float*)d_in[11];  // (256,256)
  const float* Lam = (const float*)d_in[12];  // (256,)
  float* y = (float*)d_out;                   // (8192,1,128) fp32

  float* F = (float*)d_ws;                     // ~13.4 MB used
  float* vw    = F;                            // 384*8192 (rows 256..383 = u^T)
  float* SMb   = F + 384 * NB;
  float* inv1T = SMb;                          // 16384
  float* Wm    = SMb + 16384;
  float* z1    = SMb + 32768;
  float* STt   = SMb + 49152;
  float* c2p   = SMb + 65536;
  float* inv2T = SMb + 81920;
  float* g2    = SMb + 98304;
  float* g1    = SMb + 114688;
  float* Rm    = SMb + 131072;                 // 128*384
  float* y0v   = SMb + 180224;                 // 128
  float* cx    = SMb + 180352;                 // 256
  float* xF    = SMb + 180608;                 // 256
  float* rLam  = SMb + 180864;                 // 256
  float* cpack = SMb + 181120;                 // 4*2176

  // fused pipeline: solve chain (1-130ish blocks) hides behind batch work
  mega1<<<131, 256, 0, stream>>>(u, x, C1, Fm, Lam, D11, E, vw, cx, xF, rLam,
                                 cpack, inv1T);
  mega2<<<384, 256, 0, stream>>>(D12, cx, vw, E, C2, inv1T, Wm, z1);
  mega3<<<160, 256, 0, stream>>>(cpack, rLam, vw, E, C2, Wm, z1, STt, c2p);
  mega4<<<193, 256, 0, stream>>>(D11, vw, STt, inv2T);
  mega5<<<96, 256, 0, stream>>>(cpack, rLam, vw, inv2T, c2p, g2);
  mega6<<<192, 256, 0, stream>>>(D11, vw, Wm, z1, g2, g1);
  mega7<<<225, 256, 0, stream>>>(cpack, rLam, vw, B1, B2, D21, D22, g1, g2, xF,
                                 Rm, y0v);
  mega8<<<64, 256, 0, stream>>>(D11, vw);
  mega9<<<32, 256, 0, stream>>>(cpack, rLam, vw);
  k_y<<<256, 256, 0, stream>>>(vw, Rm, y0v, y);
}